// Round 7
// baseline (108.965 us; speedup 1.0000x reference)
//
#include <hip/hip_runtime.h>

// ReactionTerm — gather ELL, SPREAD-STRIDE LDS + exact predicated loops.
//
// R6 diagnosis: random float4 LDS reads land in only 8 four-bank windows
// (addr=16*ix) -> ~13-way worst bank load -> ~40-50 cyc per ds_read_b128.
// Fix: store the 4-row group at stride 5 floats (gcd(5,32)=1) and read 4x
// ds_read_b32 -> banks uniform over all 32 -> ~2-way = free.
// Pads: per-lane exact loop bounds (exec-mask predication) mean pad slots
// are NEVER read -> no need to zero the ELL region (only cursor, 4 KB).
//
// ELL: int2[64][1024], ell[s][p] = { ia | (ib<<16), bitcast(k) };
// 1st-order ib=NS sentinel, y_s[5*NS+r]=1.0.
//
// reaction_main_kernel: block = G=4 rows x 1024 products, 512 threads.
// Thread t owns products {t, t+512}: per record 1 coalesced int2 + 8
// conflict-free ds_read_b32 + 4 FMA. No atomics, no barrier after stage.
// 4 blocks/CU x 8 waves = 32 waves/CU.

constexpr int BATCH = 4096;
constexpr int NS    = 1024;
constexpr int NR1   = 2048;
constexpr int NR2   = 8192;
constexpr int NRT   = NR1 + NR2;   // 10240
constexpr int G     = 4;
constexpr int MAIN_THREADS = 512;
constexpr int MAX_SLOTS = 64;      // Poisson(~10): P(count>64) negligible; capped both sides
constexpr int YSTRIDE = 5;         // floats per species group; gcd(5,32)=1

// d_ws layout (bytes) — no overlaps:
//   cursor : int[1024]        @ 0     (4 KiB)  <- only region that needs zeroing
//   ell    : int2[64*1024]    @ 8192  (512 KiB)
constexpr size_t WS_CURSOR = 0;
constexpr size_t WS_ELL    = 8192;

__global__ __launch_bounds__(256) void fill_kernel(
    const float* __restrict__ k1,  const float* __restrict__ k2,
    const int*   __restrict__ i1r, const int*   __restrict__ i1p,
    const int*   __restrict__ i2r, const int*   __restrict__ i2p,
    int*         __restrict__ cursor,   // [NS], zeroed
    int2*        __restrict__ ell)      // [MAX_SLOTS][NS]
{
    const int i = blockIdx.x * blockDim.x + threadIdx.x;
    if (i < NR1) {
        const int p = i1p[i];
        const int slot = atomicAdd(&cursor[p], 1);
        if (slot < MAX_SLOTS)
            ell[slot * NS + p] = make_int2(i1r[i] | (NS << 16), __float_as_int(k1[i]));
    } else if (i < NRT) {
        const int r = i - NR1;
        const int p = i2p[r];
        const int slot = atomicAdd(&cursor[p], 1);
        if (slot < MAX_SLOTS)
            ell[slot * NS + p] = make_int2(i2r[2 * r] | (i2r[2 * r + 1] << 16),
                                           __float_as_int(k2[r]));
    }
}

__global__ __launch_bounds__(MAIN_THREADS) void reaction_main_kernel(
    const float* __restrict__ t_in,    // [B]
    const float* __restrict__ y_in,    // [B, NS]
    const int*   __restrict__ counts,  // [NS] final per-product counts (=cursor)
    const int2*  __restrict__ ell,     // [MAX_SLOTS][NS]
    float*       __restrict__ y_out)   // [B, NS]
{
    __shared__ float y_s[(NS + 1) * YSTRIDE];  // (s,r) at 5*s+r; s=NS -> 1.0 sentinel

    const int tid = threadIdx.x;
    const int b0  = blockIdx.x * G;
    const float* __restrict__ yb0 = y_in + (size_t)b0 * NS;

    // Stage: coalesced global b32 loads; ds_write_b32 at stride-5 -> conflict-free.
    #pragma unroll
    for (int h = 0; h < 2; ++h) {
        const int s = tid + 512 * h;
        float* dst = y_s + YSTRIDE * s;
        dst[0] = yb0[0 * NS + s];
        dst[1] = yb0[1 * NS + s];
        dst[2] = yb0[2 * NS + s];
        dst[3] = yb0[3 * NS + s];
    }
    if (tid < 4) y_s[YSTRIDE * NS + tid] = 1.0f;   // sentinel species
    __syncthreads();

    float acc[2][4] = {{0.f, 0.f, 0.f, 0.f}, {0.f, 0.f, 0.f, 0.f}};

    #pragma unroll
    for (int h = 0; h < 2; ++h) {
        const int p = tid + 512 * h;
        const int c = min(counts[p], MAX_SLOTS);   // per-lane exact bound
        for (int s = 0; s < c; ++s) {
            const int2 r = ell[s * NS + p];        // coalesced across lanes
            const unsigned ix = (unsigned)r.x;
            const float* pa = y_s + YSTRIDE * (ix & 0xFFFFu);
            const float* pb = y_s + YSTRIDE * (ix >> 16);
            const float  k  = __int_as_float(r.y);
            acc[h][0] += k * pa[0] * pb[0];
            acc[h][1] += k * pa[1] * pb[1];
            acc[h][2] += k * pa[2] * pb[2];
            acc[h][3] += k * pa[3] * pb[3];
        }
    }

    const float t0 = t_in[b0];
    const float t1 = t_in[b0 + 1];
    const float t2 = t_in[b0 + 2];
    const float t3 = t_in[b0 + 3];

    float* __restrict__ ob0 = y_out + (size_t)b0 * NS;
    #pragma unroll
    for (int h = 0; h < 2; ++h) {
        const int p = tid + 512 * h;
        ob0[0 * NS + p] = acc[h][0] * t0;
        ob0[1 * NS + p] = acc[h][1] * t1;
        ob0[2 * NS + p] = acc[h][2] * t2;
        ob0[3 * NS + p] = acc[h][3] * t3;
    }
}

extern "C" void kernel_launch(void* const* d_in, const int* in_sizes, int n_in,
                              void* d_out, int out_size, void* d_ws, size_t ws_size,
                              hipStream_t stream) {
    const float* t_in = (const float*)d_in[0];
    const float* y_in = (const float*)d_in[1];
    const float* k1   = (const float*)d_in[2];
    const float* k2   = (const float*)d_in[3];
    const int*   i1r  = (const int*)d_in[4];
    const int*   i1p  = (const int*)d_in[5];
    const int*   i2r  = (const int*)d_in[6];
    const int*   i2p  = (const int*)d_in[7];
    float*       out  = (float*)d_out;

    char* ws = (char*)d_ws;
    int*  cursor = (int*)(ws + WS_CURSOR);
    int2* ell    = (int2*)(ws + WS_ELL);

    // Only cursor needs zeroing: pad ELL slots are never read (exact bounds).
    hipMemsetAsync(cursor, 0, NS * sizeof(int), stream);
    fill_kernel<<<dim3((NRT + 255) / 256), dim3(256), 0, stream>>>(
        k1, k2, i1r, i1p, i2r, i2p, cursor, ell);
    reaction_main_kernel<<<dim3(BATCH / G), dim3(MAIN_THREADS), 0, stream>>>(
        t_in, y_in, cursor, ell, out);
}